// Round 4
// baseline (142.268 us; speedup 1.0000x reference)
//
#include <hip/hip_runtime.h>

#define BATCH 8192
#define DIM   512
// 64 straddle + 960 full above-diag + 128 quarter tiles (last 32 parents split 4-way in j)
#define NTILE 1152

typedef __attribute__((ext_vector_type(4))) float  f32x4;
typedef __attribute__((ext_vector_type(8))) __bf16 bf16x8;

__device__ __forceinline__ unsigned short f2bf(float x) {
  unsigned u = __float_as_uint(x);
  u = (u + 0x7FFFu + ((u >> 16) & 1u)) >> 16;   // RNE
  return (unsigned short)u;
}

__device__ __forceinline__ void load_lds16(const void* g, void* l) {
  __builtin_amdgcn_global_load_lds(
      (__attribute__((address_space(1))) void*)(g),
      (__attribute__((address_space(3))) void*)(l), 16, 0, 0);
}

// counted vmcnt wait (manual: K-loop uses raw s_barrier, no compiler drain)
template<int N> __device__ __forceinline__ void waitcnt_vm() {
  if constexpr (N == 12)     asm volatile("s_waitcnt vmcnt(12)" ::: "memory");
  else if constexpr (N == 6) asm volatile("s_waitcnt vmcnt(6)"  ::: "memory");
  else if constexpr (N == 3) asm volatile("s_waitcnt vmcnt(3)"  ::: "memory");
  else                       asm volatile("s_waitcnt vmcnt(0)"  ::: "memory");
}

// raw barrier with compiler-motion guards but NO hardware vmcnt drain (m201 pattern)
__device__ __forceinline__ void barrier_nofence() {
  asm volatile("" ::: "memory");
  __builtin_amdgcn_s_barrier();
  asm volatile("" ::: "memory");
}

// monotone float <-> uint encoding (order-preserving); sentinels 0x00000000 / 0xFFFFFFFF
__device__ __forceinline__ unsigned enc(float f) {
  unsigned u = __float_as_uint(f);
  return u ^ (unsigned)(((int)u >> 31) | 0x80000000);
}
__device__ __forceinline__ float dec(unsigned k) {
  unsigned u = (k & 0x80000000u) ? (k ^ 0x80000000u) : ~k;
  return __uint_as_float(u);
}

// ---------------- prep: fp32->bf16, row norms, sentinel seeding, ctrl zeroing --------------
__global__ __launch_bounds__(256) void prep_kernel(
    const float* __restrict__ X, unsigned short* __restrict__ Xb,
    float* __restrict__ sq, unsigned* __restrict__ ctrl,
    uint4* __restrict__ pos4, uint4* __restrict__ neg4) {
  int gid = blockIdx.x * 256 + threadIdx.x;
  if (gid == 0) {
    ((float*)ctrl)[0] = 0.f;                   // sum of terms
    ((float*)ctrl)[1] = 0.f;                   // count
    ctrl[2] = 0u;                              // finish ticket
    ctrl[3] = 0u;                              // tile queue head
  }
  if (gid < 196608) {                          // 96 slots * 8192 * 4B / 16B
    pos4[gid] = (uint4){0u, 0u, 0u, 0u};       // enc-min sentinel (loses every max)
    neg4[gid] = (uint4){~0u, ~0u, ~0u, ~0u};   // enc-max sentinel (loses every min)
  }
  int wave = threadIdx.x >> 6, lane = threadIdx.x & 63;
  int row = blockIdx.x * 4 + wave;             // 2048 blocks * 4 waves = 8192 rows
  const float4* xr = (const float4*)(X + (size_t)row * DIM);
  float4 a = xr[lane * 2];
  float4 b = xr[lane * 2 + 1];
  float s = a.x*a.x + a.y*a.y + a.z*a.z + a.w*a.w
          + b.x*b.x + b.y*b.y + b.z*b.z + b.w*b.w;
  uint4 p;
  p.x = (unsigned)f2bf(a.x) | ((unsigned)f2bf(a.y) << 16);
  p.y = (unsigned)f2bf(a.z) | ((unsigned)f2bf(a.w) << 16);
  p.z = (unsigned)f2bf(b.x) | ((unsigned)f2bf(b.y) << 16);
  p.w = (unsigned)f2bf(b.z) | ((unsigned)f2bf(b.w) << 16);
  ((uint4*)(Xb + (size_t)row * DIM))[lane] = p;
  #pragma unroll
  for (int off = 32; off > 0; off >>= 1) s += __shfl_down(s, off);
  if (lane == 0) sq[row] = s;
}

// ---------------- staging: one BK=32 K-slice into a ring buffer -------------------
// Layout per ring buf (12288 shorts = 24 KB): A rows [128][32] at +0, B rows [NI*32][32] at +4096.
// Row r occupies 64 B = 4x16B chunks; storage chunk j holds logical k-chunk j^(r&3)
// (XOR swizzle on the GLOBAL source; LDS dest stays linear = base + lane*16, as
// global_load_lds requires). Read side undoes it; ds_read pattern is uniform across
// banks (2-way min aliasing = free).
template<int NI>
__device__ __forceinline__ void stage(
    const unsigned short* __restrict__ Xb, int i0, int jw, int k,
    unsigned short* buf, int wave, int lane) {
  int r4 = lane >> 2;                    // 0..15: row within 16-row block
  int sc = (lane & 3) ^ (r4 & 3);        // swizzled source chunk
  int koff = k + sc * 8;
  #pragma unroll
  for (int tt = 0; tt < 2; tt++) {       // A: 128 rows = 8 blocks of 16
    int c = wave * 2 + tt;
    load_lds16(Xb + (size_t)(i0 + c * 16 + r4) * DIM + koff, buf + c * 512);
  }
  constexpr int NB = NI / 2;             // B: NI*32 rows = NB*4 blocks of 16
  #pragma unroll
  for (int tt = 0; tt < NB; tt++) {
    int c = wave * NB + tt;
    load_lds16(Xb + (size_t)(jw + c * 16 + r4) * DIM + koff, buf + 4096 + c * 512);
  }
}

// ---------------- K-loop: ring-3, counted vmcnt, raw barriers (T3+T4) -------------
// Per step: issue stage(t+2) -> vmcnt(2S) [own buf-t loads retired, FIFO] ->
// s_barrier [all waves' buf-t loads done] -> ds_read+MFMA -> s_barrier [safe to
// overwrite buf t+2 = t-1 next iter]. Loads span 2 steps (~700cyc) >> L2 latency.
template<int NI>
__device__ __forceinline__ void gemm_tile(
    const unsigned short* __restrict__ Xb, int i0, int jw,
    unsigned short* r0, unsigned short* r1, unsigned short* r2,
    int wave, int wm, int wn, int quad, int lc, int lane,
    f32x4 (&acc)[4][8]) {
  constexpr int S = 2 + NI / 2;          // loads per thread per step (6 or 3)
  unsigned short *bc = r0, *bn = r1, *bt = r2;
  stage<NI>(Xb, i0, jw, 0,  bc, wave, lane);
  stage<NI>(Xb, i0, jw, 32, bn, wave, lane);
  int aoff = (quad ^ (lc & 3)) * 8;
  for (int t = 0; t < 16; t++) {
    if (t < 14) {
      stage<NI>(Xb, i0, jw, (t + 2) * 32, bt, wave, lane);
      waitcnt_vm<2 * S>();
    } else if (t == 14) {
      waitcnt_vm<S>();
    } else {
      waitcnt_vm<0>();
    }
    barrier_nofence();
    bf16x8 af[4], bfr[NI];
    #pragma unroll
    for (int mi = 0; mi < 4; mi++)
      af[mi] = *(const bf16x8*)&bc[(wm * 64 + mi * 16 + lc) * 32 + aoff];
    #pragma unroll
    for (int ni = 0; ni < NI; ni++)
      bfr[ni] = *(const bf16x8*)&bc[4096 + (wn * (NI * 16) + ni * 16 + lc) * 32 + aoff];
    #pragma unroll
    for (int mi = 0; mi < 4; mi++)
      #pragma unroll
      for (int ni = 0; ni < NI; ni++)
        acc[mi][ni] = __builtin_amdgcn_mfma_f32_16x16x32_bf16(
            af[mi], bfr[ni], acc[mi][ni], 0, 0, 0);
    barrier_nofence();
    unsigned short* tp = bc; bc = bn; bn = bt; bt = tp;
  }
}

// Epilogue: i-mining always; j-mining (transposed) unless STRAD (diag straddle).
template<bool STRAD, int NI, int WNS>
__device__ __forceinline__ void epilogue(
    const f32x4 (&acc)[4][8], const float* __restrict__ sq,
    const int* __restrict__ labels,
    int i0, int jwin, int wm, int wn, int quad, int lc,
    unsigned (*ibuf)[128][2], unsigned (*jbuf)[256][2]) {
  float sqj_r[NI]; int labj_r[NI];
  #pragma unroll
  for (int ni = 0; ni < NI; ni++) {
    int j = jwin + wn * WNS + ni * 16 + lc;
    sqj_r[ni] = sq[j]; labj_r[ni] = labels[j];
  }
  float rpos[16], rneg[16];
  float jp[NI], jn[NI];
  #pragma unroll
  for (int x = 0; x < NI; x++) { jp[x] = -3e38f; jn[x] = 3e38f; }
  #pragma unroll
  for (int mi = 0; mi < 4; mi++) {
    #pragma unroll
    for (int r = 0; r < 4; r++) {
      int ig = i0 + wm * 64 + mi * 16 + quad * 4 + r;
      int li = labels[ig];
      float si = sq[ig];
      float rp = -3e38f, rn = 3e38f;
      #pragma unroll
      for (int ni = 0; ni < NI; ni++) {
        float a = acc[mi][ni][r];
        float v = fmaf(-2.f, a, sqj_r[ni]);        // sq_j - 2dot (sq_i added at end)
        bool same = (li == labj_r[ni]);
        bool posok = same;
        if (STRAD) posok = same && ((jwin + wn * WNS + ni * 16 + lc) != ig);
        rp = fmaxf(rp, posok ? v : -3e38f);
        rn = fminf(rn, same ? 3e38f : v);
        if (!STRAD) {                              // j-mining: sq_i - 2dot per column
          float v2 = fmaf(-2.f, a, si);
          jp[ni] = fmaxf(jp[ni], same ? v2 : -3e38f);
          jn[ni] = fminf(jn[ni], same ? 3e38f : v2);
        }
      }
      rpos[mi * 4 + r] = rp; rneg[mi * 4 + r] = rn;
    }
  }
  #pragma unroll
  for (int m = 1; m <= 8; m <<= 1)
    #pragma unroll
    for (int x = 0; x < 16; x++) {
      rpos[x] = fmaxf(rpos[x], __shfl_xor(rpos[x], m));
      rneg[x] = fminf(rneg[x], __shfl_xor(rneg[x], m));
    }
  if (lc == 0) {
    #pragma unroll
    for (int mi = 0; mi < 4; mi++)
      #pragma unroll
      for (int r = 0; r < 4; r++) {
        int row = wm * 64 + mi * 16 + quad * 4 + r;
        ibuf[wn][row][0] = enc(rpos[mi * 4 + r]);
        ibuf[wn][row][1] = enc(rneg[mi * 4 + r]);
      }
  }
  if (!STRAD) {
    #pragma unroll
    for (int m = 16; m <= 32; m <<= 1)
      #pragma unroll
      for (int x = 0; x < NI; x++) {
        jp[x] = fmaxf(jp[x], __shfl_xor(jp[x], m));
        jn[x] = fminf(jn[x], __shfl_xor(jn[x], m));
      }
    if (quad == 0) {
      #pragma unroll
      for (int ni = 0; ni < NI; ni++) {
        int col = wn * WNS + ni * 16 + lc;
        jbuf[wm][col][0] = enc(jp[ni]);
        jbuf[wm][col][1] = enc(jn[ni]);
      }
    }
  }
}

// ---------------- main: 128x256 tiles + quarter tail + ring-3 counted-vmcnt K-loop --------
// R3 post-mortem: per-K-step fixed cost (stage+drain+barriers) ~ 2.6x MFMA time;
// the vmcnt(0) drain before each __syncthreads is the structural stall (docs: m97
// ceiling). This round: BK=32 ring-3 LDS (72KB, still 2 blocks/CU — registers cap
// occupancy anyway), counted vmcnt(12/6/3/0) + raw s_barrier so prefetches stay in
// flight across barriers (T3+T4, m218: counted vs drain0 = +38-73%). Tile geometry,
// epilogue, queue, quarter-tail (R3, -5us) all unchanged. ibuf/jbuf overlaid on
// ring[0] (dead between K-loop end [vmcnt(0) drained at t=15] and next staging,
// which is after the tile-end __syncthreads).
__global__ __launch_bounds__(256, 2) void triplet_mfma(
    const unsigned short* __restrict__ Xb, const float* __restrict__ sq,
    const int* __restrict__ labels, unsigned* __restrict__ ctrl,
    unsigned* __restrict__ pos_i, unsigned* __restrict__ neg_i,
    unsigned* __restrict__ pos_j, unsigned* __restrict__ neg_j) {
  __shared__ __align__(16) unsigned short ring[3][12288];  // 3 x 24 KB
  __shared__ int tshare;

  // overlay: ibuf at ring[0][0..1023] (2KB), jbuf at ring[0][1024..3071] (4KB)
  unsigned (*ibuf)[128][2] = reinterpret_cast<unsigned (*)[128][2]>(&ring[0][0]);
  unsigned (*jbuf)[256][2] = reinterpret_cast<unsigned (*)[256][2]>(&ring[0][1024]);

  int tid = threadIdx.x;
  int wave = tid >> 6, lane = tid & 63;
  int wm = wave >> 1, wn = wave & 1;
  int quad = lane >> 4, lc = lane & 15;

  for (;;) {
    if (tid == 0) tshare = (int)atomicAdd(&ctrl[3], 1u);
    __syncthreads();
    int t = tshare;
    if (t >= NTILE) break;

    int It = 0, Js = 0, q = -1; bool strad = false;
    if (t < 64) { It = t; Js = t >> 1; strad = true; }
    else {
      int u;
      if (t < 1024) u = t - 64;                       // full above-diag: u in [0,960)
      else { q = (t - 1024) & 3; u = 960 + ((t - 1024) >> 2); }  // quarters: u in [960,992)
      for (int s = 0; s < 64; s++) {
        int c = 31 - (s >> 1);
        if (u < c) { It = s; Js = (s >> 1) + 1 + u; break; }
        u -= c;
      }
    }
    int i0 = It * 128;
    int jw = Js * 256 + (q >= 0 ? q * 64 : 0);

    f32x4 acc[4][8];
    #pragma unroll
    for (int mi = 0; mi < 4; mi++)
      #pragma unroll
      for (int ni = 0; ni < 8; ni++)
        acc[mi][ni] = (f32x4){0.f, 0.f, 0.f, 0.f};

    if (q >= 0) {
      gemm_tile<2>(Xb, i0, jw, ring[0], ring[1], ring[2],
                   wave, wm, wn, quad, lc, lane, acc);
      epilogue<false, 2, 32>(acc, sq, labels, i0, jw, wm, wn, quad, lc, ibuf, jbuf);
    } else {
      gemm_tile<8>(Xb, i0, jw, ring[0], ring[1], ring[2],
                   wave, wm, wn, quad, lc, lane, acc);
      if (strad)
        epilogue<true, 8, 128>(acc, sq, labels, i0, jw, wm, wn, quad, lc, ibuf, jbuf);
      else
        epilogue<false, 8, 128>(acc, sq, labels, i0, jw, wm, wn, quad, lc, ibuf, jbuf);
    }
    __syncthreads();

    // in-block combine + stores to slots
    if (q >= 0) {
      // quarter: 4 siblings share i-rows of slot (Js, i0..) -> atomic merge
      if (tid < 128) {
        unsigned p = max(ibuf[0][tid][0], ibuf[1][tid][0]);
        unsigned n = min(ibuf[0][tid][1], ibuf[1][tid][1]);
        atomicMax(&pos_i[(size_t)Js * BATCH + i0 + tid], p);
        atomicMin(&neg_i[(size_t)Js * BATCH + i0 + tid], n);
      }
      if (tid < 64) {   // j-cols disjoint across siblings -> plain stores
        unsigned p = max(jbuf[0][tid][0], jbuf[1][tid][0]);
        unsigned n = min(jbuf[0][tid][1], jbuf[1][tid][1]);
        pos_j[(size_t)It * BATCH + jw + tid] = p;
        neg_j[(size_t)It * BATCH + jw + tid] = n;
      }
    } else {
      if (tid < 128) {
        unsigned p = max(ibuf[0][tid][0], ibuf[1][tid][0]);
        unsigned n = min(ibuf[0][tid][1], ibuf[1][tid][1]);
        pos_i[(size_t)Js * BATCH + i0 + tid] = p;
        neg_i[(size_t)Js * BATCH + i0 + tid] = n;
      }
      if (!strad) {
        unsigned p = max(jbuf[0][tid][0], jbuf[1][tid][0]);
        unsigned n = min(jbuf[0][tid][1], jbuf[1][tid][1]);
        pos_j[(size_t)It * BATCH + jw + tid] = p;
        neg_j[(size_t)It * BATCH + jw + tid] = n;
      }
    }
    __syncthreads();   // protect overlay reads from next tile's staging writes
  }
}

// ---------------- final: combine slots (enc-uint domain), terms, global mean ----------------
__global__ __launch_bounds__(256) void final_kernel(
    const unsigned* __restrict__ pos_i, const unsigned* __restrict__ neg_i,
    const unsigned* __restrict__ pos_j, const unsigned* __restrict__ neg_j,
    const float* __restrict__ sq, unsigned* __restrict__ ctrl,
    float* __restrict__ out) {
  int i = blockIdx.x * 256 + threadIdx.x;   // 32 blocks x 256 = 8192
  unsigned pe = 0u, ne = 0xFFFFFFFFu;       // sentinels lose every comparison
  #pragma unroll 4
  for (int s = 0; s < 32; s++) {
    pe = max(pe, pos_i[(size_t)s * BATCH + i]);
    ne = min(ne, neg_i[(size_t)s * BATCH + i]);
  }
  #pragma unroll 4
  for (int s = 0; s < 64; s++) {
    pe = max(pe, pos_j[(size_t)s * BATCH + i]);
    ne = min(ne, neg_j[(size_t)s * BATCH + i]);
  }
  float p = dec(pe), n = dec(ne);
  float term = 0.f, cnt = 0.f;
  if (p > -1e37f && n < 1e37f) {            // sentinel decodes fail => invalid row
    float si = sq[i];
    float dp = sqrtf(fmaxf(si + p, 0.f) + 1e-16f);
    float dn = sqrtf(fmaxf(si + n, 0.f) + 1e-16f);
    term = fmaxf(dp - dn + 0.3f, 0.f);
    cnt = 1.f;
  }
  #pragma unroll
  for (int off = 32; off > 0; off >>= 1) {
    term += __shfl_down(term, off);
    cnt  += __shfl_down(cnt, off);
  }
  __shared__ float ss[4], sc[4];
  int wave = threadIdx.x >> 6, lane = threadIdx.x & 63;
  if (lane == 0) { ss[wave] = term; sc[wave] = cnt; }
  __syncthreads();
  if (threadIdx.x == 0) {
    atomicAdd((float*)&ctrl[0], ss[0] + ss[1] + ss[2] + ss[3]);
    atomicAdd((float*)&ctrl[1], sc[0] + sc[1] + sc[2] + sc[3]);
    __threadfence();
    unsigned t = atomicAdd(&ctrl[2], 1u);
    if (t == 31u) {
      float S = atomicAdd((float*)&ctrl[0], 0.f);
      float C = atomicAdd((float*)&ctrl[1], 0.f);
      out[0] = S / fmaxf(C, 1.f);
    }
  }
}

extern "C" void kernel_launch(void* const* d_in, const int* in_sizes, int n_in,
                              void* d_out, int out_size, void* d_ws, size_t ws_size,
                              hipStream_t stream) {
  const float* X      = (const float*)d_in[0];
  const int*   labels = (const int*)d_in[1];
  float* out = (float*)d_out;
  char* ws = (char*)d_ws;

  const size_t SLOT = (size_t)BATCH * 4;                 // 32 KB per slot
  unsigned short* Xb = (unsigned short*)ws;              // 8 MB
  float* sq      = (float*)(ws + (8u << 20));            // 32 KB
  unsigned* ctrl = (unsigned*)(ws + (8u << 20) + (32u << 10)); // sums|ticket|queue
  char*  posb = ws + (8u << 20) + (64u << 10);           // 96 slots = 3 MB
  char*  negb = posb + 96 * SLOT;                        // 96 slots = 3 MB
  unsigned* pos_i = (unsigned*)posb;                     // 32 slots keyed Js
  unsigned* pos_j = (unsigned*)(posb + 32 * SLOT);       // 64 slots keyed It
  unsigned* neg_i = (unsigned*)negb;
  unsigned* neg_j = (unsigned*)(negb + 32 * SLOT);

  prep_kernel<<<BATCH / 4, 256, 0, stream>>>(X, Xb, sq, ctrl,
                                             (uint4*)posb, (uint4*)negb);
  triplet_mfma<<<512, 256, 0, stream>>>(Xb, sq, labels, ctrl,
                                        pos_i, neg_i, pos_j, neg_j);
  final_kernel<<<BATCH / 256, 256, 0, stream>>>(pos_i, neg_i, pos_j, neg_j, sq, ctrl, out);
}

// Round 5
// 139.426 us; speedup vs baseline: 1.0204x; 1.0204x over previous
//
#include <hip/hip_runtime.h>

#define BATCH 8192
#define DIM   512
// 64 straddle + 960 full above-diag + 128 quarter tiles (last 32 parents split 4-way in j)
#define NTILE 1152

typedef __attribute__((ext_vector_type(4))) float  f32x4;
typedef __attribute__((ext_vector_type(8))) __bf16 bf16x8;

__device__ __forceinline__ unsigned short f2bf(float x) {
  unsigned u = __float_as_uint(x);
  u = (u + 0x7FFFu + ((u >> 16) & 1u)) >> 16;   // RNE
  return (unsigned short)u;
}

__device__ __forceinline__ void load_lds16(const void* g, void* l) {
  __builtin_amdgcn_global_load_lds(
      (__attribute__((address_space(1))) void*)(g),
      (__attribute__((address_space(3))) void*)(l), 16, 0, 0);
}

// raw barrier with compiler-motion guards but NO hardware vmcnt drain (m201 pattern)
__device__ __forceinline__ void barrier_nofence() {
  asm volatile("" ::: "memory");
  __builtin_amdgcn_s_barrier();
  asm volatile("" ::: "memory");
}
__device__ __forceinline__ void wait_vm0() {
  asm volatile("s_waitcnt vmcnt(0)" ::: "memory");
}

// monotone float <-> uint encoding (order-preserving); sentinels 0x00000000 / 0xFFFFFFFF
__device__ __forceinline__ unsigned enc(float f) {
  unsigned u = __float_as_uint(f);
  return u ^ (unsigned)(((int)u >> 31) | 0x80000000);
}
__device__ __forceinline__ float dec(unsigned k) {
  unsigned u = (k & 0x80000000u) ? (k ^ 0x80000000u) : ~k;
  return __uint_as_float(u);
}

// ---------------- prep: fp32->bf16, row norms, sentinel seeding, ctrl zeroing --------------
__global__ __launch_bounds__(256) void prep_kernel(
    const float* __restrict__ X, unsigned short* __restrict__ Xb,
    float* __restrict__ sq, unsigned* __restrict__ ctrl,
    uint4* __restrict__ pos4, uint4* __restrict__ neg4) {
  int gid = blockIdx.x * 256 + threadIdx.x;
  if (gid == 0) {
    ((float*)ctrl)[0] = 0.f;                   // sum of terms
    ((float*)ctrl)[1] = 0.f;                   // count
    ctrl[2] = 0u;                              // finish ticket
    ctrl[3] = 0u;                              // tile queue head
  }
  if (gid < 196608) {                          // 96 slots * 8192 * 4B / 16B
    pos4[gid] = (uint4){0u, 0u, 0u, 0u};       // enc-min sentinel (loses every max)
    neg4[gid] = (uint4){~0u, ~0u, ~0u, ~0u};   // enc-max sentinel (loses every min)
  }
  int wave = threadIdx.x >> 6, lane = threadIdx.x & 63;
  int row = blockIdx.x * 4 + wave;             // 2048 blocks * 4 waves = 8192 rows
  const float4* xr = (const float4*)(X + (size_t)row * DIM);
  float4 a = xr[lane * 2];
  float4 b = xr[lane * 2 + 1];
  float s = a.x*a.x + a.y*a.y + a.z*a.z + a.w*a.w
          + b.x*b.x + b.y*b.y + b.z*b.z + b.w*b.w;
  uint4 p;
  p.x = (unsigned)f2bf(a.x) | ((unsigned)f2bf(a.y) << 16);
  p.y = (unsigned)f2bf(a.z) | ((unsigned)f2bf(a.w) << 16);
  p.z = (unsigned)f2bf(b.x) | ((unsigned)f2bf(b.y) << 16);
  p.w = (unsigned)f2bf(b.z) | ((unsigned)f2bf(b.w) << 16);
  ((uint4*)(Xb + (size_t)row * DIM))[lane] = p;
  #pragma unroll
  for (int off = 32; off > 0; off >>= 1) s += __shfl_down(s, off);
  if (lane == 0) sq[row] = s;
}

// ---------------- staging: one BK=32 K-slice into a ring buffer -------------------
// Pair-row layout, 128B line = 2 rows (fixes R4's 64B-stride bank conflicts):
//   addr(r,c) = (r>>1)*128 + (r&1)*64 + (c ^ ((r>>1)&3))*16   [within 16-row block]
// global_load_lds writes linear (base + lane*16), so the permutation is applied to
// the per-lane GLOBAL source address; read side applies the same XOR.
template<int NI>
__device__ __forceinline__ void stage(
    const unsigned short* __restrict__ Xb, int i0, int jw, int k,
    unsigned short* buf, int wave, int lane) {
  int p = lane >> 3;                     // pair-row 0..7
  int h = (lane >> 2) & 1;               // half of pair
  int r = p * 2 + h;                     // row within 16-row block
  int c = (lane & 3) ^ (p & 3);          // logical 16B chunk (k-offset)
  int koff = k + c * 8;
  #pragma unroll
  for (int tt = 0; tt < 2; tt++) {       // A: 128 rows = 8 blocks of 16
    int cb = wave * 2 + tt;
    load_lds16(Xb + (size_t)(i0 + cb * 16 + r) * DIM + koff, buf + cb * 512);
  }
  constexpr int NB = NI / 2;             // B: NI*2 blocks of 16
  #pragma unroll
  for (int tt = 0; tt < NB; tt++) {
    int cb = wave * NB + tt;
    load_lds16(Xb + (size_t)(jw + cb * 16 + r) * DIM + koff, buf + 4096 + cb * 512);
  }
}

// ---------------- K-loop: ring-2, T3-minimal 2-phase ------------------------------
// Per step t: issue stage(t+1) into buf[cur^1] FIRST, then ds_read+MFMA on buf[cur]
// (loads fly under ~32 MFMAs), then vmcnt(0)+s_barrier (residual wait only).
// One barrier per step: reads of buf[cur^1] at t-1 are lgkm-complete before
// B_{t-1}; its writes are issued after B_{t-1}; vmcnt(0) before B_t guarantees
// buf[cur^1] complete before anyone reads it at t+1.
template<int NI>
__device__ __forceinline__ void gemm_tile(
    const unsigned short* __restrict__ Xb, int i0, int jw,
    unsigned short* b0, unsigned short* b1,
    int wave, int wm, int wn, int quad, int lc, int lane,
    f32x4 (&acc)[4][8]) {
  stage<NI>(Xb, i0, jw, 0, b0, wave, lane);
  wait_vm0();
  barrier_nofence();
  int rbase = (lc >> 1) * 64 + (lc & 1) * 32;        // shorts within block
  int csw   = (quad ^ ((lc >> 1) & 3)) * 8;          // swizzled chunk (shorts)
  unsigned short* bc = b0;
  unsigned short* bn = b1;
  for (int t = 0; t < 16; t++) {
    if (t < 15) stage<NI>(Xb, i0, jw, (t + 1) * 32, bn, wave, lane);
    bf16x8 af[4], bfr[NI];
    #pragma unroll
    for (int mi = 0; mi < 4; mi++)
      af[mi] = *(const bf16x8*)&bc[(wm * 4 + mi) * 512 + rbase + csw];
    #pragma unroll
    for (int ni = 0; ni < NI; ni++)
      bfr[ni] = *(const bf16x8*)&bc[4096 + (wn * NI + ni) * 512 + rbase + csw];
    #pragma unroll
    for (int mi = 0; mi < 4; mi++)
      #pragma unroll
      for (int ni = 0; ni < NI; ni++)
        acc[mi][ni] = __builtin_amdgcn_mfma_f32_16x16x32_bf16(
            af[mi], bfr[ni], acc[mi][ni], 0, 0, 0);
    if (t < 15) {
      wait_vm0();
      barrier_nofence();
    }
    unsigned short* tp = bc; bc = bn; bn = tp;
  }
}

// Epilogue: i-mining always; j-mining (transposed) unless STRAD (diag straddle).
template<bool STRAD, int NI, int WNS>
__device__ __forceinline__ void epilogue(
    const f32x4 (&acc)[4][8], const float* __restrict__ sq,
    const int* __restrict__ labels,
    int i0, int jwin, int wm, int wn, int quad, int lc,
    unsigned (*ibuf)[128][2], unsigned (*jbuf)[256][2]) {
  float sqj_r[NI]; int labj_r[NI];
  #pragma unroll
  for (int ni = 0; ni < NI; ni++) {
    int j = jwin + wn * WNS + ni * 16 + lc;
    sqj_r[ni] = sq[j]; labj_r[ni] = labels[j];
  }
  float rpos[16], rneg[16];
  float jp[NI], jn[NI];
  #pragma unroll
  for (int x = 0; x < NI; x++) { jp[x] = -3e38f; jn[x] = 3e38f; }
  #pragma unroll
  for (int mi = 0; mi < 4; mi++) {
    #pragma unroll
    for (int r = 0; r < 4; r++) {
      int ig = i0 + wm * 64 + mi * 16 + quad * 4 + r;
      int li = labels[ig];
      float si = sq[ig];
      float rp = -3e38f, rn = 3e38f;
      #pragma unroll
      for (int ni = 0; ni < NI; ni++) {
        float a = acc[mi][ni][r];
        float v = fmaf(-2.f, a, sqj_r[ni]);        // sq_j - 2dot (sq_i added at end)
        bool same = (li == labj_r[ni]);
        bool posok = same;
        if (STRAD) posok = same && ((jwin + wn * WNS + ni * 16 + lc) != ig);
        rp = fmaxf(rp, posok ? v : -3e38f);
        rn = fminf(rn, same ? 3e38f : v);
        if (!STRAD) {                              // j-mining: sq_i - 2dot per column
          float v2 = fmaf(-2.f, a, si);
          jp[ni] = fmaxf(jp[ni], same ? v2 : -3e38f);
          jn[ni] = fminf(jn[ni], same ? 3e38f : v2);
        }
      }
      rpos[mi * 4 + r] = rp; rneg[mi * 4 + r] = rn;
    }
  }
  #pragma unroll
  for (int m = 1; m <= 8; m <<= 1)
    #pragma unroll
    for (int x = 0; x < 16; x++) {
      rpos[x] = fmaxf(rpos[x], __shfl_xor(rpos[x], m));
      rneg[x] = fminf(rneg[x], __shfl_xor(rneg[x], m));
    }
  if (lc == 0) {
    #pragma unroll
    for (int mi = 0; mi < 4; mi++)
      #pragma unroll
      for (int r = 0; r < 4; r++) {
        int row = wm * 64 + mi * 16 + quad * 4 + r;
        ibuf[wn][row][0] = enc(rpos[mi * 4 + r]);
        ibuf[wn][row][1] = enc(rneg[mi * 4 + r]);
      }
  }
  if (!STRAD) {
    #pragma unroll
    for (int m = 16; m <= 32; m <<= 1)
      #pragma unroll
      for (int x = 0; x < NI; x++) {
        jp[x] = fmaxf(jp[x], __shfl_xor(jp[x], m));
        jn[x] = fminf(jn[x], __shfl_xor(jn[x], m));
      }
    if (quad == 0) {
      #pragma unroll
      for (int ni = 0; ni < NI; ni++) {
        int col = wn * WNS + ni * 16 + lc;
        jbuf[wm][col][0] = enc(jp[ni]);
        jbuf[wm][col][1] = enc(jn[ni]);
      }
    }
  }
}

// ---------------- main: 128x256 tiles + quarter tail + ring-2 pipelined K-loop -----------
// R4 post-mortem: 64B-row LDS (4-way bank conflicts, 3.3M cycles) + doubled barrier
// count ate the pipeline gain. This round: T3-minimal 2-phase (m248): BK=32 ring-2
// (48KB, 2 blocks/CU), ONE barrier per step, stage(t+1) issued BEFORE compute of t
// so loads hide under 32 MFMAs; vmcnt(0) only after compute. Pair-row 128B-line LDS
// layout restores the R0-class conflict-free ds_read pattern. Tile geometry,
// epilogue, queue, quarter-tail (R3) unchanged. ibuf/jbuf overlaid on ring[0]
// (last read at t=14, ordered by B_14; epilogue writes follow it).
__global__ __launch_bounds__(256, 2) void triplet_mfma(
    const unsigned short* __restrict__ Xb, const float* __restrict__ sq,
    const int* __restrict__ labels, unsigned* __restrict__ ctrl,
    unsigned* __restrict__ pos_i, unsigned* __restrict__ neg_i,
    unsigned* __restrict__ pos_j, unsigned* __restrict__ neg_j) {
  __shared__ __align__(16) unsigned short ring[2][12288];  // 2 x 24 KB
  __shared__ int tshare;

  // overlay: ibuf at ring[0][0..1023] (2KB), jbuf at ring[0][1024..3071] (4KB)
  unsigned (*ibuf)[128][2] = reinterpret_cast<unsigned (*)[128][2]>(&ring[0][0]);
  unsigned (*jbuf)[256][2] = reinterpret_cast<unsigned (*)[256][2]>(&ring[0][1024]);

  int tid = threadIdx.x;
  int wave = tid >> 6, lane = tid & 63;
  int wm = wave >> 1, wn = wave & 1;
  int quad = lane >> 4, lc = lane & 15;

  for (;;) {
    if (tid == 0) tshare = (int)atomicAdd(&ctrl[3], 1u);
    __syncthreads();
    int t = tshare;
    if (t >= NTILE) break;

    int It = 0, Js = 0, q = -1; bool strad = false;
    if (t < 64) { It = t; Js = t >> 1; strad = true; }
    else {
      int u;
      if (t < 1024) u = t - 64;                       // full above-diag: u in [0,960)
      else { q = (t - 1024) & 3; u = 960 + ((t - 1024) >> 2); }  // quarters: u in [960,992)
      for (int s = 0; s < 64; s++) {
        int c = 31 - (s >> 1);
        if (u < c) { It = s; Js = (s >> 1) + 1 + u; break; }
        u -= c;
      }
    }
    int i0 = It * 128;
    int jw = Js * 256 + (q >= 0 ? q * 64 : 0);

    f32x4 acc[4][8];
    #pragma unroll
    for (int mi = 0; mi < 4; mi++)
      #pragma unroll
      for (int ni = 0; ni < 8; ni++)
        acc[mi][ni] = (f32x4){0.f, 0.f, 0.f, 0.f};

    if (q >= 0) {
      gemm_tile<2>(Xb, i0, jw, ring[0], ring[1], wave, wm, wn, quad, lc, lane, acc);
      epilogue<false, 2, 32>(acc, sq, labels, i0, jw, wm, wn, quad, lc, ibuf, jbuf);
    } else {
      gemm_tile<8>(Xb, i0, jw, ring[0], ring[1], wave, wm, wn, quad, lc, lane, acc);
      if (strad)
        epilogue<true, 8, 128>(acc, sq, labels, i0, jw, wm, wn, quad, lc, ibuf, jbuf);
      else
        epilogue<false, 8, 128>(acc, sq, labels, i0, jw, wm, wn, quad, lc, ibuf, jbuf);
    }
    __syncthreads();

    // in-block combine + stores to slots
    if (q >= 0) {
      // quarter: 4 siblings share i-rows of slot (Js, i0..) -> atomic merge
      if (tid < 128) {
        unsigned p = max(ibuf[0][tid][0], ibuf[1][tid][0]);
        unsigned n = min(ibuf[0][tid][1], ibuf[1][tid][1]);
        atomicMax(&pos_i[(size_t)Js * BATCH + i0 + tid], p);
        atomicMin(&neg_i[(size_t)Js * BATCH + i0 + tid], n);
      }
      if (tid < 64) {   // j-cols disjoint across siblings -> plain stores
        unsigned p = max(jbuf[0][tid][0], jbuf[1][tid][0]);
        unsigned n = min(jbuf[0][tid][1], jbuf[1][tid][1]);
        pos_j[(size_t)It * BATCH + jw + tid] = p;
        neg_j[(size_t)It * BATCH + jw + tid] = n;
      }
    } else {
      if (tid < 128) {
        unsigned p = max(ibuf[0][tid][0], ibuf[1][tid][0]);
        unsigned n = min(ibuf[0][tid][1], ibuf[1][tid][1]);
        pos_i[(size_t)Js * BATCH + i0 + tid] = p;
        neg_i[(size_t)Js * BATCH + i0 + tid] = n;
      }
      if (!strad) {
        unsigned p = max(jbuf[0][tid][0], jbuf[1][tid][0]);
        unsigned n = min(jbuf[0][tid][1], jbuf[1][tid][1]);
        pos_j[(size_t)It * BATCH + jw + tid] = p;
        neg_j[(size_t)It * BATCH + jw + tid] = n;
      }
    }
    __syncthreads();   // protect overlay reads from next tile's staging writes
  }
}

// ---------------- final: combine slots (enc-uint domain), terms, global mean ----------------
__global__ __launch_bounds__(256) void final_kernel(
    const unsigned* __restrict__ pos_i, const unsigned* __restrict__ neg_i,
    const unsigned* __restrict__ pos_j, const unsigned* __restrict__ neg_j,
    const float* __restrict__ sq, unsigned* __restrict__ ctrl,
    float* __restrict__ out) {
  int i = blockIdx.x * 256 + threadIdx.x;   // 32 blocks x 256 = 8192
  unsigned pe = 0u, ne = 0xFFFFFFFFu;       // sentinels lose every comparison
  #pragma unroll 4
  for (int s = 0; s < 32; s++) {
    pe = max(pe, pos_i[(size_t)s * BATCH + i]);
    ne = min(ne, neg_i[(size_t)s * BATCH + i]);
  }
  #pragma unroll 4
  for (int s = 0; s < 64; s++) {
    pe = max(pe, pos_j[(size_t)s * BATCH + i]);
    ne = min(ne, neg_j[(size_t)s * BATCH + i]);
  }
  float p = dec(pe), n = dec(ne);
  float term = 0.f, cnt = 0.f;
  if (p > -1e37f && n < 1e37f) {            // sentinel decodes fail => invalid row
    float si = sq[i];
    float dp = sqrtf(fmaxf(si + p, 0.f) + 1e-16f);
    float dn = sqrtf(fmaxf(si + n, 0.f) + 1e-16f);
    term = fmaxf(dp - dn + 0.3f, 0.f);
    cnt = 1.f;
  }
  #pragma unroll
  for (int off = 32; off > 0; off >>= 1) {
    term += __shfl_down(term, off);
    cnt  += __shfl_down(cnt, off);
  }
  __shared__ float ss[4], sc[4];
  int wave = threadIdx.x >> 6, lane = threadIdx.x & 63;
  if (lane == 0) { ss[wave] = term; sc[wave] = cnt; }
  __syncthreads();
  if (threadIdx.x == 0) {
    atomicAdd((float*)&ctrl[0], ss[0] + ss[1] + ss[2] + ss[3]);
    atomicAdd((float*)&ctrl[1], sc[0] + sc[1] + sc[2] + sc[3]);
    __threadfence();
    unsigned t = atomicAdd(&ctrl[2], 1u);
    if (t == 31u) {
      float S = atomicAdd((float*)&ctrl[0], 0.f);
      float C = atomicAdd((float*)&ctrl[1], 0.f);
      out[0] = S / fmaxf(C, 1.f);
    }
  }
}

extern "C" void kernel_launch(void* const* d_in, const int* in_sizes, int n_in,
                              void* d_out, int out_size, void* d_ws, size_t ws_size,
                              hipStream_t stream) {
  const float* X      = (const float*)d_in[0];
  const int*   labels = (const int*)d_in[1];
  float* out = (float*)d_out;
  char* ws = (char*)d_ws;

  const size_t SLOT = (size_t)BATCH * 4;                 // 32 KB per slot
  unsigned short* Xb = (unsigned short*)ws;              // 8 MB
  float* sq      = (float*)(ws + (8u << 20));            // 32 KB
  unsigned* ctrl = (unsigned*)(ws + (8u << 20) + (32u << 10)); // sums|ticket|queue
  char*  posb = ws + (8u << 20) + (64u << 10);           // 96 slots = 3 MB
  char*  negb = posb + 96 * SLOT;                        // 96 slots = 3 MB
  unsigned* pos_i = (unsigned*)posb;                     // 32 slots keyed Js
  unsigned* pos_j = (unsigned*)(posb + 32 * SLOT);       // 64 slots keyed It
  unsigned* neg_i = (unsigned*)negb;
  unsigned* neg_j = (unsigned*)(negb + 32 * SLOT);

  prep_kernel<<<BATCH / 4, 256, 0, stream>>>(X, Xb, sq, ctrl,
                                             (uint4*)posb, (uint4*)negb);
  triplet_mfma<<<512, 256, 0, stream>>>(Xb, sq, labels, ctrl,
                                        pos_i, neg_i, pos_j, neg_j);
  final_kernel<<<BATCH / 256, 256, 0, stream>>>(pos_i, neg_i, pos_j, neg_j, sq, ctrl, out);
}